// Round 7
// baseline (226.299 us; speedup 1.0000x reference)
//
#include <hip/hip_runtime.h>
#include <math.h>

// B=16, N=1024, C_IN=256, C_OUT=256, POOL_RATIO=0.5
#define Bsz 16
#define Nn  1024

// d_out layout (float32): x_out[16,1024,256], adj_out[16,1024,1024], new_mask[16,1024], new_n[16]
#define ADJ_OFF    (16*1024*256)
#define MASK_OFF   (ADJ_OFF + 16*1024*1024)
#define NN_OFF     (MASK_OFF + 16*1024)

typedef unsigned long long u64;
typedef unsigned short u16;
typedef short bf16x8 __attribute__((ext_vector_type(8)));
typedef float f32x4  __attribute__((ext_vector_type(4)));

static __device__ inline u16 f2bf(float f) {
    unsigned u = __float_as_uint(f);
    u += 0x7fffu + ((u >> 16) & 1u);
    return (u16)(u >> 16);
}

// =============== k1: x->bf16 + z = x.(W.pool) (blocks 0-255) | W^T bf16 (blocks 256-271) ===============
__global__ __launch_bounds__(256) void k1(const float* __restrict__ x,
                                          const float* __restrict__ W,
                                          const float* __restrict__ pool,
                                          u16* __restrict__ XB,
                                          u16* __restrict__ WT,
                                          float* __restrict__ Z) {
    int bid = blockIdx.x, t = threadIdx.x, lane = t & 63, wid = t >> 6;
    if (bid < 256) {
        __shared__ float sp[256];
        __shared__ float swp[256];
        sp[t] = pool[t];
        __syncthreads();
        float acc = 0.f;
        const float* wr = W + t * 256;
        for (int j = 0; j < 256; j += 4) {
            float4 w4 = *(const float4*)&wr[j];
            acc = fmaf(w4.x, sp[j], fmaf(w4.y, sp[j + 1],
                  fmaf(w4.z, sp[j + 2], fmaf(w4.w, sp[j + 3], acc))));
        }
        swp[t] = acc;
        __syncthreads();
        const float* w4p = &swp[lane * 4];
        float wx = w4p[0], wy = w4p[1], wz = w4p[2], ww = w4p[3];
        int base = bid * 64 + wid * 16;
        #pragma unroll 1
        for (int rb = 0; rb < 4; ++rb) {
            float4 v[4];
            #pragma unroll
            for (int k = 0; k < 4; ++k)
                v[k] = ((const float4*)(x + (size_t)(base + rb * 4 + k) * 256))[lane];
            #pragma unroll
            for (int k = 0; k < 4; ++k) {
                int row = base + rb * 4 + k;
                ushort4 o;
                o.x = f2bf(v[k].x); o.y = f2bf(v[k].y); o.z = f2bf(v[k].z); o.w = f2bf(v[k].w);
                ((ushort4*)(XB + (size_t)row * 256))[lane] = o;
                float a = fmaf(v[k].x, wx, fmaf(v[k].y, wy, fmaf(v[k].z, wz, v[k].w * ww)));
                for (int off = 32; off > 0; off >>= 1) a += __shfl_down(a, off, 64);
                if (lane == 0) Z[row] = a;
            }
        }
    } else {
        __shared__ float sT[64][65];
        int bt = bid - 256;
        int tr = (bt >> 2) * 64, tc = (bt & 3) * 64;
        #pragma unroll
        for (int p = 0; p < 4; ++p) {
            int r = p * 16 + (t >> 4), c = (t & 15) * 4;
            float4 w = *(const float4*)&W[(size_t)(tr + r) * 256 + tc + c];
            sT[r][c] = w.x; sT[r][c + 1] = w.y; sT[r][c + 2] = w.z; sT[r][c + 3] = w.w;
        }
        __syncthreads();
        #pragma unroll
        for (int p = 0; p < 2; ++p) {
            int nl = p * 32 + (t >> 3), kl = (t & 7) * 8;
            u16 tmp[8];
            #pragma unroll
            for (int j = 0; j < 8; ++j) tmp[j] = f2bf(sT[kl + j][nl]);
            *(int4*)&WT[(size_t)(tc + nl) * 256 + tr + kl] = *(const int4*)tmp;
        }
    }
}

// =============== k2: XWBT = (XB@WT^T)^T per batch (blocks 0-255) | y = adj.z (blocks 256-1279) ===============
__global__ __launch_bounds__(256) void k2(const u16* __restrict__ XB,
                                          const u16* __restrict__ WT,
                                          const float* __restrict__ adj,
                                          const float* __restrict__ Z,
                                          u16* __restrict__ XWBT,
                                          float* __restrict__ Y) {
    int t = threadIdx.x, lane = t & 63, wid = t >> 6;
    if (blockIdx.x < 256) {
        __shared__ short sA[128][72];
        __shared__ short sB[128][72];
        int bm = blockIdx.x >> 1, bn = blockIdx.x & 1;
        int wr = (wid >> 1) * 64, wc = (wid & 1) * 64;
        int fm = lane & 15, fq = lane >> 4;

        f32x4 acc[4][4];
        #pragma unroll
        for (int i = 0; i < 4; ++i)
            #pragma unroll
            for (int j = 0; j < 4; ++j)
                acc[i][j] = (f32x4){0.f, 0.f, 0.f, 0.f};

        int sr = t >> 1, half = (t & 1) * 32;
        const u16* gA = XB + ((size_t)(bm * 128 + sr)) * 256 + half;
        const u16* gB = WT + ((size_t)(bn * 128 + sr)) * 256 + half;

        for (int kt = 0; kt < 4; ++kt) {
            __syncthreads();
            #pragma unroll
            for (int q = 0; q < 4; ++q) {
                *(int4*)&sA[sr][half + q * 8] = *(const int4*)&gA[kt * 64 + q * 8];
                *(int4*)&sB[sr][half + q * 8] = *(const int4*)&gB[kt * 64 + q * 8];
            }
            __syncthreads();
            #pragma unroll
            for (int ks = 0; ks < 64; ks += 32) {
                bf16x8 af[4], bfv[4];
                #pragma unroll
                for (int i = 0; i < 4; ++i)
                    af[i] = *(const bf16x8*)&sA[wr + i * 16 + fm][ks + fq * 8];
                #pragma unroll
                for (int j = 0; j < 4; ++j)
                    bfv[j] = *(const bf16x8*)&sB[wc + j * 16 + fm][ks + fq * 8];
                #pragma unroll
                for (int i = 0; i < 4; ++i)
                    #pragma unroll
                    for (int j = 0; j < 4; ++j)
                        acc[i][j] = __builtin_amdgcn_mfma_f32_16x16x32_bf16(af[i], bfv[j], acc[i][j], 0, 0, 0);
            }
        }
        // write transposed: XWBT[b][n][m_local], m contiguous
        int b = bm >> 3;
        #pragma unroll
        for (int i = 0; i < 4; ++i) {
            int rloc = (bm & 7) * 128 + wr + i * 16 + fq * 4;
            #pragma unroll
            for (int j = 0; j < 4; ++j) {
                int c = bn * 128 + wc + j * 16 + fm;
                u16 tmp[4];
                #pragma unroll
                for (int r = 0; r < 4; ++r) tmp[r] = f2bf(acc[i][j][r]);
                *(unsigned long long*)&XWBT[(size_t)b * 262144 + (size_t)c * 1024 + rloc] =
                    *(const unsigned long long*)tmp;
            }
        }
    } else {
        int g = blockIdx.x - 256;
        int b = g >> 6, grp = g & 63;
        __shared__ float sZ[1024];
        ((float4*)sZ)[t] = ((const float4*)(Z + (b << 10)))[t];
        __syncthreads();
        const float* z0 = &sZ[lane * 4];
        #pragma unroll 1
        for (int rr = 0; rr < 4; ++rr) {
            int row = (b << 10) + grp * 16 + wid * 4 + rr;
            const float4* ar = (const float4*)(adj + (size_t)row * 1024);
            float4 v0 = ar[lane], v1 = ar[64 + lane], v2 = ar[128 + lane], v3 = ar[192 + lane];
            float a = v0.x * z0[0] + v0.y * z0[1] + v0.z * z0[2] + v0.w * z0[3];
            a += v1.x * z0[256] + v1.y * z0[257] + v1.z * z0[258] + v1.w * z0[259];
            a += v2.x * z0[512] + v2.y * z0[513] + v2.z * z0[514] + v2.w * z0[515];
            a += v3.x * z0[768] + v3.y * z0[769] + v3.z * z0[770] + v3.w * z0[771];
            for (int off = 32; off > 0; off >>= 1) a += __shfl_down(a, off, 64);
            if (lane == 0) Y[row] = a;
        }
    }
}

// =============== k3: rank-count mask (no sort) + scale + bitmap ===============
// remove_i <=> mask_i && #{masked j: (y_j,j) < (y_i,i)} < n_remove   == reference sorted-rank semantics
__global__ __launch_bounds__(256) void k3(const float* __restrict__ Y,
                                          const int* __restrict__ maskIn,
                                          const int* __restrict__ nNodes,
                                          const float* __restrict__ bias,
                                          const float* __restrict__ pool,
                                          float* __restrict__ SCALE,
                                          float* __restrict__ NM,
                                          float* __restrict__ newN,
                                          u64* __restrict__ NMBITS) {
    __shared__ float sy[1024];
    __shared__ int   sm[1024];
    __shared__ float redb[4], redq[4];
    __shared__ float sBP, sINV;
    int b = blockIdx.x >> 2, part = blockIdx.x & 3;
    int t = threadIdx.x, lane = t & 63, wid = t >> 6;
    int base = b << 10;

    for (int j = t; j < 1024; j += 256) {
        sy[j] = Y[base + j];
        sm[j] = maskIn[base + j];
    }
    {
        float pv = pool[t];
        float bv = bias[t] * pv;
        float qv = pv * pv;
        for (int off = 32; off > 0; off >>= 1) {
            bv += __shfl_down(bv, off, 64);
            qv += __shfl_down(qv, off, 64);
        }
        if (lane == 0) { redb[wid] = bv; redq[wid] = qv; }
    }
    __syncthreads();
    if (t == 0) {
        sBP  = redb[0] + redb[1] + redb[2] + redb[3];
        sINV = 1.0f / sqrtf(redq[0] + redq[1] + redq[2] + redq[3]);
    }
    __syncthreads();

    int i = part * 256 + t;
    float yi = sy[i];
    int cnt = 0;
    #pragma unroll 4
    for (int j = 0; j < 1024; ++j) {
        float yj = sy[j];
        bool less = (yj < yi) || (yj == yi && j < i);
        cnt += less ? sm[j] : 0;
    }
    int nn = nNodes[b];
    int nrem = (int)((float)nn * 0.5f);
    int mi = sm[i];
    int nm = (mi == 1 && cnt < nrem) ? 0 : mi;
    NM[base + i] = (float)nm;
    SCALE[base + i] = nm ? tanhf((yi + sBP) * sINV) : 0.0f;
    u64 bm = __ballot(nm != 0);
    if (lane == 0) NMBITS[b * 16 + part * 4 + wid] = bm;
    if (t == 0 && part == 0) newN[b] = (float)(nn - nrem);
}

// =============== k4: H = adj_bf16 @ XWBT^T with fused AO write + x_out epilogue ===============
// grid 512: b = blk>>5, m-tile of 32 rows, N-tile = 256 (full). adj read exactly once; AO written during A-staging.
__global__ __launch_bounds__(256) void k4(const float* __restrict__ adj,
                                          const u16* __restrict__ XWBT,
                                          const float* __restrict__ SCALE,
                                          const float* __restrict__ bias,
                                          const u64* __restrict__ NMBITS,
                                          float* __restrict__ XO,
                                          float* __restrict__ AO) {
    __shared__ short sA[32][72];
    __shared__ short sB[256][72];
    __shared__ u64 sBits[16];
    int t = threadIdx.x, lane = t & 63, wid = t >> 6;
    int b = blockIdx.x >> 5, mt = blockIdx.x & 31;
    int m0 = mt * 32;
    if (t < 16) sBits[t] = NMBITS[b * 16 + t];

    int wc = wid * 64;
    int fm = lane & 15, fq = lane >> 4;

    f32x4 acc[2][4];
    #pragma unroll
    for (int i = 0; i < 2; ++i)
        #pragma unroll
        for (int j = 0; j < 4; ++j)
            acc[i][j] = (f32x4){0.f, 0.f, 0.f, 0.f};

    // A/AO staging mapping: row ar = t>>3 (0..31), cols c8 = (t&7)*8 (8 floats)
    int ar = t >> 3, c8 = (t & 7) * 8;
    const float* adjR = adj + ((size_t)((b << 10) + m0 + ar)) * 1024 + c8;
    float*       aoR  = AO  + ((size_t)((b << 10) + m0 + ar)) * 1024 + c8;
    const u16*   xwB  = XWBT + (size_t)b * 262144;

    __syncthreads();          // sBits visible
    int rloc = m0 + ar;
    float rowM = (float)((sBits[rloc >> 6] >> (rloc & 63)) & 1ULL);

    for (int kt = 0; kt < 16; ++kt) {
        int k0 = kt * 64;
        __syncthreads();
        // ---- stage A (fp32 adj -> bf16) + fused AO write ----
        {
            float4 v0 = *(const float4*)&adjR[k0];
            float4 v1 = *(const float4*)&adjR[k0 + 4];
            unsigned cb = (unsigned)((sBits[(k0 + c8) >> 6] >> ((k0 + c8) & 63)) & 0xffULL);
            float4 o0, o1;
            o0.x = (cb & 1u)   ? v0.x * rowM : 0.f;
            o0.y = (cb & 2u)   ? v0.y * rowM : 0.f;
            o0.z = (cb & 4u)   ? v0.z * rowM : 0.f;
            o0.w = (cb & 8u)   ? v0.w * rowM : 0.f;
            o1.x = (cb & 16u)  ? v1.x * rowM : 0.f;
            o1.y = (cb & 32u)  ? v1.y * rowM : 0.f;
            o1.z = (cb & 64u)  ? v1.z * rowM : 0.f;
            o1.w = (cb & 128u) ? v1.w * rowM : 0.f;
            *(float4*)&aoR[k0] = o0;
            *(float4*)&aoR[k0 + 4] = o1;
            u16 tmp[8];
            tmp[0] = f2bf(v0.x); tmp[1] = f2bf(v0.y); tmp[2] = f2bf(v0.z); tmp[3] = f2bf(v0.w);
            tmp[4] = f2bf(v1.x); tmp[5] = f2bf(v1.y); tmp[6] = f2bf(v1.z); tmp[7] = f2bf(v1.w);
            *(int4*)&sA[ar][c8] = *(const int4*)tmp;
        }
        // ---- stage B: XWBT[b][n][k0..k0+64), 32 KB ----
        {
            int nb = t >> 3;
            #pragma unroll
            for (int pass = 0; pass < 8; ++pass) {
                int n = nb + pass * 32;
                *(int4*)&sB[n][c8] = *(const int4*)&xwB[(size_t)n * 1024 + k0 + c8];
            }
        }
        __syncthreads();
        // ---- MFMA ----
        #pragma unroll
        for (int ks = 0; ks < 64; ks += 32) {
            bf16x8 af[2], bfv[4];
            #pragma unroll
            for (int i = 0; i < 2; ++i)
                af[i] = *(const bf16x8*)&sA[i * 16 + fm][ks + fq * 8];
            #pragma unroll
            for (int j = 0; j < 4; ++j)
                bfv[j] = *(const bf16x8*)&sB[wc + j * 16 + fm][ks + fq * 8];
            #pragma unroll
            for (int i = 0; i < 2; ++i)
                #pragma unroll
                for (int j = 0; j < 4; ++j)
                    acc[i][j] = __builtin_amdgcn_mfma_f32_16x16x32_bf16(af[i], bfv[j], acc[i][j], 0, 0, 0);
        }
    }

    // ---- epilogue: XO = (H + bias) * SCALE ----
    float bj[4];
    #pragma unroll
    for (int j = 0; j < 4; ++j) bj[j] = bias[wc + j * 16 + fm];
    int mb = (b << 10) + m0;
    #pragma unroll
    for (int i = 0; i < 2; ++i) {
        int r0 = mb + i * 16 + fq * 4;
        float s0 = SCALE[r0], s1 = SCALE[r0 + 1], s2 = SCALE[r0 + 2], s3 = SCALE[r0 + 3];
        #pragma unroll
        for (int j = 0; j < 4; ++j) {
            int c = wc + j * 16 + fm;
            float* xo = XO + (size_t)r0 * 256 + c;
            xo[0]   = (acc[i][j][0] + bj[j]) * s0;
            xo[256] = (acc[i][j][1] + bj[j]) * s1;
            xo[512] = (acc[i][j][2] + bj[j]) * s2;
            xo[768] = (acc[i][j][3] + bj[j]) * s3;
        }
    }
}

extern "C" void kernel_launch(void* const* d_in, const int* in_sizes, int n_in,
                              void* d_out, int out_size, void* d_ws, size_t ws_size,
                              hipStream_t stream) {
    const float* x      = (const float*)d_in[0];
    const float* adj    = (const float*)d_in[1];
    const int*   mask   = (const int*)d_in[2];
    const int*   nnodes = (const int*)d_in[3];
    const float* W      = (const float*)d_in[4];
    const float* bias   = (const float*)d_in[5];
    const float* pool   = (const float*)d_in[6];

    float* out = (float*)d_out;
    float* XO  = out;
    float* AO  = out + ADJ_OFF;
    float* NM  = out + MASK_OFF;
    float* NNo = out + NN_OFF;

    char* w = (char*)d_ws;
    u16*   XB     = (u16*)(w);                    //  8,388,608 B
    u16*   WT     = (u16*)(w + 8388608);          //    131,072
    u16*   XWBT   = (u16*)(w + 8519680);          //  8,388,608
    float* Z      = (float*)(w + 16908288);       //     65,536
    float* Y      = (float*)(w + 16973824);       //     65,536
    float* SCALE  = (float*)(w + 17039360);       //     65,536
    u64*   NMBITS = (u64*)(w + 17104896);         //      2,048

    k1<<<272, 256, 0, stream>>>(x, W, pool, XB, WT, Z);
    k2<<<1280, 256, 0, stream>>>(XB, WT, adj, Z, XWBT, Y);
    k3<<<Bsz * 4, 256, 0, stream>>>(Y, mask, nnodes, bias, pool, SCALE, NM, NNo, NMBITS);
    k4<<<512, 256, 0, stream>>>(adj, XWBT, SCALE, bias, NMBITS, XO, AO);
}

// Round 8
// 226.014 us; speedup vs baseline: 1.0013x; 1.0013x over previous
//
#include <hip/hip_runtime.h>
#include <math.h>

// B=16, N=1024, C_IN=256, C_OUT=256, POOL_RATIO=0.5
#define Bsz 16
#define Nn  1024

// d_out layout (float32): x_out[16,1024,256], adj_out[16,1024,1024], new_mask[16,1024], new_n[16]
#define ADJ_OFF    (16*1024*256)
#define MASK_OFF   (ADJ_OFF + 16*1024*1024)
#define NN_OFF     (MASK_OFF + 16*1024)

typedef unsigned long long u64;
typedef unsigned int u32;
typedef unsigned short u16;
typedef short bf16x8 __attribute__((ext_vector_type(8)));
typedef float f32x4  __attribute__((ext_vector_type(4)));

static __device__ inline u16 f2bf(float f) {
    unsigned u = __float_as_uint(f);
    u += 0x7fffu + ((u >> 16) & 1u);
    return (u16)(u >> 16);
}

__device__ inline u64 shfl_xor_u64(u64 v, int m) {
    int lo = __shfl_xor((int)(v & 0xffffffffULL), m, 64);
    int hi = __shfl_xor((int)(v >> 32), m, 64);
    return ((u64)(unsigned)hi << 32) | (unsigned)lo;
}

// =============== k1: x->bf16 + z = x.(W.pool) (blocks 0-255) | W^T bf16 (blocks 256-271) ===============
__global__ __launch_bounds__(256) void k1(const float* __restrict__ x,
                                          const float* __restrict__ W,
                                          const float* __restrict__ pool,
                                          u16* __restrict__ XB,
                                          u16* __restrict__ WT,
                                          float* __restrict__ Z) {
    int bid = blockIdx.x, t = threadIdx.x, lane = t & 63, wid = t >> 6;
    if (bid < 256) {
        __shared__ float sp[256];
        __shared__ float swp[256];
        sp[t] = pool[t];
        __syncthreads();
        float acc = 0.f;
        const float* wr = W + t * 256;
        for (int j = 0; j < 256; j += 4) {
            float4 w4 = *(const float4*)&wr[j];
            acc = fmaf(w4.x, sp[j], fmaf(w4.y, sp[j + 1],
                  fmaf(w4.z, sp[j + 2], fmaf(w4.w, sp[j + 3], acc))));
        }
        swp[t] = acc;
        __syncthreads();
        const float* w4p = &swp[lane * 4];
        float wx = w4p[0], wy = w4p[1], wz = w4p[2], ww = w4p[3];
        int base = bid * 64 + wid * 16;
        #pragma unroll 1
        for (int rb = 0; rb < 4; ++rb) {
            float4 v[4];
            #pragma unroll
            for (int k = 0; k < 4; ++k)
                v[k] = ((const float4*)(x + (size_t)(base + rb * 4 + k) * 256))[lane];
            #pragma unroll
            for (int k = 0; k < 4; ++k) {
                int row = base + rb * 4 + k;
                ushort4 o;
                o.x = f2bf(v[k].x); o.y = f2bf(v[k].y); o.z = f2bf(v[k].z); o.w = f2bf(v[k].w);
                ((ushort4*)(XB + (size_t)row * 256))[lane] = o;
                float a = fmaf(v[k].x, wx, fmaf(v[k].y, wy, fmaf(v[k].z, wz, v[k].w * ww)));
                for (int off = 32; off > 0; off >>= 1) a += __shfl_down(a, off, 64);
                if (lane == 0) Z[row] = a;
            }
        }
    } else {
        __shared__ float sT[64][65];
        int bt = bid - 256;
        int tr = (bt >> 2) * 64, tc = (bt & 3) * 64;
        #pragma unroll
        for (int p = 0; p < 4; ++p) {
            int r = p * 16 + (t >> 4), c = (t & 15) * 4;
            float4 w = *(const float4*)&W[(size_t)(tr + r) * 256 + tc + c];
            sT[r][c] = w.x; sT[r][c + 1] = w.y; sT[r][c + 2] = w.z; sT[r][c + 3] = w.w;
        }
        __syncthreads();
        #pragma unroll
        for (int p = 0; p < 2; ++p) {
            int nl = p * 32 + (t >> 3), kl = (t & 7) * 8;
            u16 tmp[8];
            #pragma unroll
            for (int j = 0; j < 8; ++j) tmp[j] = f2bf(sT[kl + j][nl]);
            *(int4*)&WT[(size_t)(tc + nl) * 256 + tr + kl] = *(const int4*)tmp;
        }
    }
}

// =============== k2: XWBT GEMM (blocks 0-255) | y = adj.z + ABITS emission (blocks 256-1279) ===============
__global__ __launch_bounds__(256) void k2(const u16* __restrict__ XB,
                                          const u16* __restrict__ WT,
                                          const float* __restrict__ adj,
                                          const float* __restrict__ Z,
                                          u16* __restrict__ XWBT,
                                          u64* __restrict__ ABITS,
                                          float* __restrict__ Y) {
    int t = threadIdx.x, lane = t & 63, wid = t >> 6;
    if (blockIdx.x < 256) {
        __shared__ short sA[128][72];
        __shared__ short sB[128][72];
        int bm = blockIdx.x >> 1, bn = blockIdx.x & 1;
        int wr = (wid >> 1) * 64, wc = (wid & 1) * 64;
        int fm = lane & 15, fq = lane >> 4;

        f32x4 acc[4][4];
        #pragma unroll
        for (int i = 0; i < 4; ++i)
            #pragma unroll
            for (int j = 0; j < 4; ++j)
                acc[i][j] = (f32x4){0.f, 0.f, 0.f, 0.f};

        int sr = t >> 1, half = (t & 1) * 32;
        const u16* gA = XB + ((size_t)(bm * 128 + sr)) * 256 + half;
        const u16* gB = WT + ((size_t)(bn * 128 + sr)) * 256 + half;

        for (int kt = 0; kt < 4; ++kt) {
            __syncthreads();
            #pragma unroll
            for (int q = 0; q < 4; ++q) {
                *(int4*)&sA[sr][half + q * 8] = *(const int4*)&gA[kt * 64 + q * 8];
                *(int4*)&sB[sr][half + q * 8] = *(const int4*)&gB[kt * 64 + q * 8];
            }
            __syncthreads();
            #pragma unroll
            for (int ks = 0; ks < 64; ks += 32) {
                bf16x8 af[4], bfv[4];
                #pragma unroll
                for (int i = 0; i < 4; ++i)
                    af[i] = *(const bf16x8*)&sA[wr + i * 16 + fm][ks + fq * 8];
                #pragma unroll
                for (int j = 0; j < 4; ++j)
                    bfv[j] = *(const bf16x8*)&sB[wc + j * 16 + fm][ks + fq * 8];
                #pragma unroll
                for (int i = 0; i < 4; ++i)
                    #pragma unroll
                    for (int j = 0; j < 4; ++j)
                        acc[i][j] = __builtin_amdgcn_mfma_f32_16x16x32_bf16(af[i], bfv[j], acc[i][j], 0, 0, 0);
            }
        }
        // write transposed: XWBT[b][n][m_local], m contiguous
        int b = bm >> 3;
        #pragma unroll
        for (int i = 0; i < 4; ++i) {
            int rloc = (bm & 7) * 128 + wr + i * 16 + fq * 4;
            #pragma unroll
            for (int j = 0; j < 4; ++j) {
                int c = bn * 128 + wc + j * 16 + fm;
                u16 tmp[4];
                #pragma unroll
                for (int r = 0; r < 4; ++r) tmp[r] = f2bf(acc[i][j][r]);
                *(unsigned long long*)&XWBT[(size_t)b * 262144 + (size_t)c * 1024 + rloc] =
                    *(const unsigned long long*)tmp;
            }
        }
    } else {
        int g = blockIdx.x - 256;
        int b = g >> 6, grp = g & 63;
        __shared__ float sZ[1024];
        ((float4*)sZ)[t] = ((const float4*)(Z + (b << 10)))[t];
        __syncthreads();
        const float* z0 = &sZ[lane * 4];
        int sh4 = (lane & 15) * 4, grp16 = lane >> 4;
        #pragma unroll 1
        for (int rr = 0; rr < 4; ++rr) {
            int row = (b << 10) + grp * 16 + wid * 4 + rr;
            const float4* ar = (const float4*)(adj + (size_t)row * 1024);
            float4 v0 = ar[lane], v1 = ar[64 + lane], v2 = ar[128 + lane], v3 = ar[192 + lane];
            // y accumulation
            float a = v0.x * z0[0] + v0.y * z0[1] + v0.z * z0[2] + v0.w * z0[3];
            a += v1.x * z0[256] + v1.y * z0[257] + v1.z * z0[258] + v1.w * z0[259];
            a += v2.x * z0[512] + v2.y * z0[513] + v2.z * z0[514] + v2.w * z0[515];
            a += v3.x * z0[768] + v3.y * z0[769] + v3.z * z0[770] + v3.w * z0[771];
            // bit emission: nibble per lane per 256-chunk, OR-reduce across 16-lane groups
            u64 nib[4];
            nib[0] = (u64)((v0.x != 0.f) | ((v0.y != 0.f) << 1) | ((v0.z != 0.f) << 2) | ((v0.w != 0.f) << 3));
            nib[1] = (u64)((v1.x != 0.f) | ((v1.y != 0.f) << 1) | ((v1.z != 0.f) << 2) | ((v1.w != 0.f) << 3));
            nib[2] = (u64)((v2.x != 0.f) | ((v2.y != 0.f) << 1) | ((v2.z != 0.f) << 2) | ((v2.w != 0.f) << 3));
            nib[3] = (u64)((v3.x != 0.f) | ((v3.y != 0.f) << 1) | ((v3.z != 0.f) << 2) | ((v3.w != 0.f) << 3));
            #pragma unroll
            for (int ch = 0; ch < 4; ++ch) {
                u64 part = nib[ch] << sh4;
                part |= shfl_xor_u64(part, 1);
                part |= shfl_xor_u64(part, 2);
                part |= shfl_xor_u64(part, 4);
                part |= shfl_xor_u64(part, 8);
                if ((lane & 15) == 0) ABITS[(size_t)row * 16 + ch * 4 + grp16] = part;
            }
            for (int off = 32; off > 0; off >>= 1) a += __shfl_down(a, off, 64);
            if (lane == 0) Y[row] = a;
        }
    }
}

// =============== k3: rank-count mask + scale + bitmap ===============
__global__ __launch_bounds__(256) void k3(const float* __restrict__ Y,
                                          const int* __restrict__ maskIn,
                                          const int* __restrict__ nNodes,
                                          const float* __restrict__ bias,
                                          const float* __restrict__ pool,
                                          float* __restrict__ SCALE,
                                          float* __restrict__ NM,
                                          float* __restrict__ newN,
                                          u64* __restrict__ NMBITS) {
    __shared__ float sy[1024];
    __shared__ int   sm[1024];
    __shared__ float redb[4], redq[4];
    __shared__ float sBP, sINV;
    int b = blockIdx.x >> 2, part = blockIdx.x & 3;
    int t = threadIdx.x, lane = t & 63, wid = t >> 6;
    int base = b << 10;

    for (int j = t; j < 1024; j += 256) {
        sy[j] = Y[base + j];
        sm[j] = maskIn[base + j];
    }
    {
        float pv = pool[t];
        float bv = bias[t] * pv;
        float qv = pv * pv;
        for (int off = 32; off > 0; off >>= 1) {
            bv += __shfl_down(bv, off, 64);
            qv += __shfl_down(qv, off, 64);
        }
        if (lane == 0) { redb[wid] = bv; redq[wid] = qv; }
    }
    __syncthreads();
    if (t == 0) {
        sBP  = redb[0] + redb[1] + redb[2] + redb[3];
        sINV = 1.0f / sqrtf(redq[0] + redq[1] + redq[2] + redq[3]);
    }
    __syncthreads();

    int i = part * 256 + t;
    float yi = sy[i];
    int cnt = 0;
    #pragma unroll 4
    for (int j = 0; j < 1024; ++j) {
        float yj = sy[j];
        bool less = (yj < yi) || (yj == yi && j < i);
        cnt += less ? sm[j] : 0;
    }
    int nn = nNodes[b];
    int nrem = (int)((float)nn * 0.5f);
    int mi = sm[i];
    int nm = (mi == 1 && cnt < nrem) ? 0 : mi;
    NM[base + i] = (float)nm;
    SCALE[base + i] = nm ? tanhf((yi + sBP) * sINV) : 0.0f;
    u64 bm = __ballot(nm != 0);
    if (lane == 0) NMBITS[b * 16 + part * 4 + wid] = bm;
    if (t == 0 && part == 0) newN[b] = (float)(nn - nrem);
}

// =============== k4: H GEMM from ABITS + x_out epilogue (blocks 0-255) | AO writer from bits (blocks 256-1279) ===============
__global__ __launch_bounds__(256) void k4(const u64* __restrict__ ABITS,
                                          const u16* __restrict__ XWBT,
                                          const float* __restrict__ SCALE,
                                          const float* __restrict__ bias,
                                          const u64* __restrict__ NMBITS,
                                          float* __restrict__ XO,
                                          float* __restrict__ AO) {
    int t = threadIdx.x, lane = t & 63, wid = t >> 6;
    if (blockIdx.x < 256) {
        __shared__ short sA[128][72];
        __shared__ short sB[128][72];
        int idx = blockIdx.x;
        int bn = idx & 1, bmt = (idx >> 1) & 7, b = idx >> 4;
        int wr = (wid >> 1) * 64, wc = (wid & 1) * 64;
        int fm = lane & 15, fq = lane >> 4;

        f32x4 acc[4][4];
        #pragma unroll
        for (int i = 0; i < 4; ++i)
            #pragma unroll
            for (int j = 0; j < 4; ++j)
                acc[i][j] = (f32x4){0.f, 0.f, 0.f, 0.f};

        int r = t >> 1, h = t & 1;
        const u64* abr = ABITS + (size_t)((b << 10) + bmt * 128 + r) * 16;
        int sr = r, half = h * 32;
        const u16* gB = XWBT + (size_t)b * 262144 + (size_t)(bn * 128 + sr) * 1024 + half;

        for (int kt = 0; kt < 16; ++kt) {
            __syncthreads();
            // stage A: expand 32 bits -> 32 bf16
            u32 bits = (u32)(abr[kt] >> (h * 32));
            #pragma unroll
            for (int q = 0; q < 4; ++q) {
                u32 w2[4] __attribute__((aligned(16)));
                #pragma unroll
                for (int i2 = 0; i2 < 4; ++i2) {
                    int bi = q * 8 + i2 * 2;
                    w2[i2] = (((bits >> bi) & 1u) ? 0x3F80u : 0u) |
                             (((bits >> (bi + 1)) & 1u) ? 0x3F800000u : 0u);
                }
                *(int4*)&sA[r][half + q * 8] = *(const int4*)w2;
            }
            // stage B
            #pragma unroll
            for (int q = 0; q < 4; ++q)
                *(int4*)&sB[sr][half + q * 8] = *(const int4*)&gB[kt * 64 + q * 8];
            __syncthreads();
            #pragma unroll
            for (int ks = 0; ks < 64; ks += 32) {
                bf16x8 af[4], bfv[4];
                #pragma unroll
                for (int i = 0; i < 4; ++i)
                    af[i] = *(const bf16x8*)&sA[wr + i * 16 + fm][ks + fq * 8];
                #pragma unroll
                for (int j = 0; j < 4; ++j)
                    bfv[j] = *(const bf16x8*)&sB[wc + j * 16 + fm][ks + fq * 8];
                #pragma unroll
                for (int i = 0; i < 4; ++i)
                    #pragma unroll
                    for (int j = 0; j < 4; ++j)
                        acc[i][j] = __builtin_amdgcn_mfma_f32_16x16x32_bf16(af[i], bfv[j], acc[i][j], 0, 0, 0);
            }
        }
        float bj[4];
        #pragma unroll
        for (int j = 0; j < 4; ++j) bj[j] = bias[bn * 128 + wc + j * 16 + fm];
        int mb = (b << 10) + bmt * 128 + wr;
        #pragma unroll
        for (int i = 0; i < 4; ++i) {
            int r0 = mb + i * 16 + fq * 4;
            float s0 = SCALE[r0], s1 = SCALE[r0 + 1], s2 = SCALE[r0 + 2], s3 = SCALE[r0 + 3];
            #pragma unroll
            for (int j = 0; j < 4; ++j) {
                int c = bn * 128 + wc + j * 16 + fm;
                float* xo = XO + (size_t)r0 * 256 + c;
                xo[0]   = (acc[i][j][0] + bj[j]) * s0;
                xo[256] = (acc[i][j][1] + bj[j]) * s1;
                xo[512] = (acc[i][j][2] + bj[j]) * s2;
                xo[768] = (acc[i][j][3] + bj[j]) * s3;
            }
        }
    } else {
        int g = blockIdx.x - 256;          // 0..1023, 16 rows each
        int b = g >> 6;
        int base = g * 16;
        __shared__ u64 sNM[16];
        if (t < 16) sNM[t] = NMBITS[b * 16 + t];
        __syncthreads();
        int w = t >> 4, sh = (t & 15) * 4;
        u32 colNib = (u32)((sNM[w] >> sh) & 0xFULL);
        #pragma unroll 1
        for (int r = 0; r < 16; ++r) {
            int row = base + r;
            int rloc = row & 1023;
            int nmRow = (int)((sNM[rloc >> 6] >> (rloc & 63)) & 1ULL);
            float4 o = make_float4(0.f, 0.f, 0.f, 0.f);
            if (nmRow) {
                u32 aN = ((u32)((ABITS[(size_t)row * 16 + w] >> sh) & 0xFULL)) & colNib;
                o.x = (aN & 1u) ? 1.f : 0.f;
                o.y = (aN & 2u) ? 1.f : 0.f;
                o.z = (aN & 4u) ? 1.f : 0.f;
                o.w = (aN & 8u) ? 1.f : 0.f;
            }
            ((float4*)(AO + (size_t)row * 1024))[t] = o;
        }
    }
}

extern "C" void kernel_launch(void* const* d_in, const int* in_sizes, int n_in,
                              void* d_out, int out_size, void* d_ws, size_t ws_size,
                              hipStream_t stream) {
    const float* x      = (const float*)d_in[0];
    const float* adj    = (const float*)d_in[1];
    const int*   mask   = (const int*)d_in[2];
    const int*   nnodes = (const int*)d_in[3];
    const float* W      = (const float*)d_in[4];
    const float* bias   = (const float*)d_in[5];
    const float* pool   = (const float*)d_in[6];

    float* out = (float*)d_out;
    float* XO  = out;
    float* AO  = out + ADJ_OFF;
    float* NM  = out + MASK_OFF;
    float* NNo = out + NN_OFF;

    char* w = (char*)d_ws;
    u16*   XB     = (u16*)(w);                    //  8,388,608 B
    u16*   WT     = (u16*)(w + 8388608);          //    131,072
    u16*   XWBT   = (u16*)(w + 8519680);          //  8,388,608
    u64*   ABITS  = (u64*)(w + 16908288);         //  2,097,152
    float* Z      = (float*)(w + 19005440);       //     65,536
    float* Y      = (float*)(w + 19070976);       //     65,536
    float* SCALE  = (float*)(w + 19136512);       //     65,536
    u64*   NMBITS = (u64*)(w + 19202048);         //      2,048

    k1<<<272, 256, 0, stream>>>(x, W, pool, XB, WT, Z);
    k2<<<1280, 256, 0, stream>>>(XB, WT, adj, Z, XWBT, ABITS, Y);
    k3<<<Bsz * 4, 256, 0, stream>>>(Y, mask, nnodes, bias, pool, SCALE, NM, NNo, NMBITS);
    k4<<<1280, 256, 0, stream>>>(ABITS, XWBT, SCALE, bias, NMBITS, XO, AO);
}